// Round 3
// baseline (9.718 us; speedup 1.0000x reference)
//
#include <hip/hip_runtime.h>

#define AE_EPS 1e-6f

// Problem-structure constants (from reference setup_inputs):
//   B=32 images, P=30 persons, K=17 keypoints, D=4 tag dims, N=17*128*128.
constexpr int AE_P = 30;
constexpr int AE_K = 17;
constexpr int AE_D = 4;
constexpr int AE_THREADS = AE_P * 32;   // 960: one 32-lane half-wave per person
constexpr int AE_WAVES = AE_THREADS / 64;

__global__ __launch_bounds__(AE_THREADS)
void aeloss_kernel(const float* __restrict__ tags,
                   const int*  __restrict__ kps,
                   float* __restrict__ out,
                   int N)
{
    const int b   = blockIdx.x;
    const int tid = threadIdx.x;
    const int p   = tid >> 5;      // person 0..29
    const int k   = tid & 31;      // lane within person group (k<17 active)

    __shared__ float mean_lds[AE_P][AE_D];
    __shared__ float pull_lds[AE_P];
    __shared__ float valid_lds[AE_P];
    __shared__ float part_lds[AE_WAVES];

    const float* tb = tags + (size_t)b * (size_t)N * AE_D;
    const int*   kb = kps  + (size_t)b * AE_P * AE_K * 2;

    // ---- Phase 1: gather + one-pass moment partials, half-wave per person ----
    float m = 0.0f, s0 = 0.0f, s1 = 0.0f, s2 = 0.0f, s3 = 0.0f, stt = 0.0f;
    if (k < AE_K) {
        const int2 kv = *reinterpret_cast<const int2*>(kb + 2 * (p * AE_K + k));
        const float4 t = *reinterpret_cast<const float4*>(tb + (size_t)kv.x * AE_D);
        m  = (kv.y > 0) ? 1.0f : 0.0f;
        s0 = m * t.x; s1 = m * t.y; s2 = m * t.z; s3 = m * t.w;
        stt = m * (t.x*t.x + t.y*t.y + t.z*t.z + t.w*t.w);
    }
    // shuffle reduce within the 32-lane person group
    #pragma unroll
    for (int off = 16; off > 0; off >>= 1) {
        m   += __shfl_down(m,   off, 32);
        s0  += __shfl_down(s0,  off, 32);
        s1  += __shfl_down(s1,  off, 32);
        s2  += __shfl_down(s2,  off, 32);
        s3  += __shfl_down(s3,  off, 32);
        stt += __shfl_down(stt, off, 32);
    }
    if (k == 0) {
        const float cnt  = m;
        const float safe = fmaxf(cnt, 1.0f);
        const float inv  = 1.0f / safe;
        const float mu0 = s0 * inv, mu1 = s1 * inv, mu2 = s2 * inv, mu3 = s3 * inv;
        mean_lds[p][0] = mu0;
        mean_lds[p][1] = mu1;
        mean_lds[p][2] = mu2;
        mean_lds[p][3] = mu3;
        const float valid = (cnt > 0.0f) ? 1.0f : 0.0f;
        valid_lds[p] = valid;
        // pull_p = (Sum m|t|^2 - Sum m t . mu) / safe  (sum-of-squares identity)
        const float pull = (stt - (s0*mu0 + s1*mu1 + s2*mu2 + s3*mu3)) * inv;
        pull_lds[p] = pull * valid;
    }
    __syncthreads();

    // ---- Phase 2: pairwise push, one pair candidate per thread ----
    float push = 0.0f;
    if (tid < AE_P * AE_P) {
        const int pi = tid / AE_P, pj = tid % AE_P;
        if (pi < pj && valid_lds[pi] > 0.0f && valid_lds[pj] > 0.0f) {
            const float d0 = mean_lds[pi][0] - mean_lds[pj][0];
            const float d1 = mean_lds[pi][1] - mean_lds[pj][1];
            const float d2 = mean_lds[pi][2] - mean_lds[pj][2];
            const float d3 = mean_lds[pi][3] - mean_lds[pj][3];
            const float diff = d0*d0 + d1*d1 + d2*d2 + d3*d3;
            if (diff != 0.0f) push = __expf(-diff);
        }
    }

    // pull/n live only in threads 0..29 (wave 0)
    float pull = (tid < AE_P) ? pull_lds[tid]  : 0.0f;
    float nval = (tid < AE_P) ? valid_lds[tid] : 0.0f;

    #pragma unroll
    for (int off = 32; off > 0; off >>= 1) {
        push += __shfl_down(push, off, 64);
    }
    if (tid < 64) {   // wave-uniform branch: only wave 0 carries pull/n
        #pragma unroll
        for (int off = 32; off > 0; off >>= 1) {
            pull += __shfl_down(pull, off, 64);
            nval += __shfl_down(nval, off, 64);
        }
    }
    if ((tid & 63) == 0) part_lds[tid >> 6] = push;
    __syncthreads();

    if (tid == 0) {
        float tpush = 0.0f;
        #pragma unroll
        for (int w = 0; w < AE_WAVES; ++w) tpush += part_lds[w];
        const float n = nval;   // thread 0 holds the full pull/n reduction
        out[2 * b + 0] = tpush / ((n - 1.0f) * n + AE_EPS);
        out[2 * b + 1] = pull  / (n + AE_EPS);
    }
}

extern "C" void kernel_launch(void* const* d_in, const int* in_sizes, int n_in,
                              void* d_out, int out_size, void* d_ws, size_t ws_size,
                              hipStream_t stream)
{
    const float* tags = (const float*)d_in[0];   // (B, N, D) float32
    const int*   kps  = (const int*)d_in[1];     // (B, P, K, 2) int (narrowed from int64)
    float* out = (float*)d_out;                  // (B, 2) float32

    const int B = out_size / 2;                            // 32
    const int N = (int)(in_sizes[0] / ((size_t)B * AE_D)); // 278528

    aeloss_kernel<<<B, AE_THREADS, 0, stream>>>(tags, kps, out, N);
}